// Round 9
// baseline (211.542 us; speedup 1.0000x reference)
//
#include <hip/hip_runtime.h>
#include <hip/hip_bf16.h>
#include <math.h>

#define B_SEG 64
#define HDIM 256
#define HDIV 128
#define NHEADS 4
#define DH 32
#define QSC 0.17677669529663687f

typedef unsigned short u16;
typedef unsigned int u32;

typedef __attribute__((ext_vector_type(8))) short s8v;   // 8 x bf16
typedef __attribute__((ext_vector_type(4))) short s4v;   // 4 x bf16 (2 VGPR)
typedef __attribute__((ext_vector_type(4))) float f4v;   // mfma accum

// 16x16x16 bf16 MFMA: device pass picks the available builtin spelling;
// host pass gets an inert stub (host never executes device bodies, it only
// needs the file to parse — R6 lesson: __has_builtin fails on the host pass).
#if defined(__HIP_DEVICE_COMPILE__)
#if __has_builtin(__builtin_amdgcn_mfma_f32_16x16x16_bf16)
#define MFMA16(a, b, c) __builtin_amdgcn_mfma_f32_16x16x16_bf16(a, b, c, 0, 0, 0)
#elif __has_builtin(__builtin_amdgcn_mfma_f32_16x16x16bf16_1k)
#define MFMA16(a, b, c) __builtin_amdgcn_mfma_f32_16x16x16bf16_1k(a, b, c, 0, 0, 0)
#else
#error "no 16x16x16 bf16 mfma builtin on device"
#endif
#else
#define MFMA16(a, b, c) (c)
#endif

__device__ __forceinline__ u16 f2bf(float f) {
    u32 v;
    __builtin_memcpy(&v, &f, 4);
    u32 r = v + 0x7fffu + ((v >> 16) & 1u);
    return (u16)(r >> 16);
}

// async global->LDS, 16B per lane. LDS dest = wave-uniform base + lane*16.
__device__ __forceinline__ void async_cp16(const u16* g, u16* l) {
    __builtin_amdgcn_global_load_lds(
        (const __attribute__((address_space(1))) u32*)g,
        (__attribute__((address_space(3))) u32*)l, 16, 0, 0);
}

// ============ prep: weights (bf16 + head-deinterleave + Wm-folding), meta,
// ============ activation f32->bf16 convert — one launch.
// head permute: dest channel c' = h*32+d <-> src c = d*4+h.
// pW1f = [W1[:,0:256] | W1[:,256:384] @ Wm'] (256 x 384); b1 absorbs W1b@bm.
__global__ __launch_bounds__(256) void k_prep(
    const float* __restrict__ Wq, const float* __restrict__ bq,
    const float* __restrict__ Wk, const float* __restrict__ bk,
    const float* __restrict__ Wv, const float* __restrict__ bv,
    const float* __restrict__ Wm, const float* __restrict__ bm,
    const float* __restrict__ W1, const float* __restrict__ b1,
    const float* __restrict__ g1, const float* __restrict__ be1,
    const float* __restrict__ rm1, const float* __restrict__ rv1,
    const float* __restrict__ W2, const float* __restrict__ b2,
    const float* __restrict__ g2, const float* __restrict__ be2,
    const float* __restrict__ rm2, const float* __restrict__ rv2,
    const int* __restrict__ sc_raw, const int* __restrict__ dc_raw,
    const float* __restrict__ src_h, const float* __restrict__ dst_h,
    int* __restrict__ meta,
    u16* __restrict__ pWq, u16* __restrict__ pWkv,
    u16* __restrict__ pW1f, u16* __restrict__ pW2,
    float* __restrict__ bqp, float* __restrict__ bkvp,
    float* __restrict__ sc1, float* __restrict__ sh1,
    float* __restrict__ sc2, float* __restrict__ sh2,
    u16* __restrict__ srcb, u16* __restrict__ dstb, int ntot) {
    if (blockIdx.x < 1028) {
        int idx = blockIdx.x * 256 + threadIdx.x;
        if (idx < 32768) {                       // Wq' rows permuted
            int cp = idx >> 8, k = idx & 255;
            int c = ((cp & 31) << 2) | (cp >> 5);
            pWq[idx] = f2bf(Wq[c * 256 + k]);
        } else if (idx < 98304) {                // Wkv': k rows 0..127, v 128..255
            int i = idx - 32768;
            int rp = i >> 8, k = i & 255;
            int r = rp & 127;
            int c = ((r & 31) << 2) | (r >> 5);
            float v = (rp < 128) ? Wk[c * 256 + k] : Wv[c * 256 + k];
            pWkv[i] = f2bf(v);
        } else if (idx < 163840) {               // W1 cols 0..255 plain
            int i = idx - 98304;
            int o = i >> 8, k = i & 255;
            pW1f[o * 384 + k] = f2bf(W1[o * 384 + k]);
        } else if (idx < 196608) {               // W1bm = W1b @ Wm' (cols 256..383)
            int i = idx - 163840;
            int o = i >> 7, cp = i & 127;
            int c = ((cp & 31) << 2) | (cp >> 5);
            float acc = 0.f;
            for (int j = 0; j < 128; j++)
                acc += W1[o * 384 + 256 + j] * Wm[j * 128 + c];
            pW1f[o * 384 + 256 + cp] = f2bf(acc);
        } else if (idx < 262144) {               // W2 plain
            int i = idx - 196608;
            pW2[i] = f2bf(W2[i]);
        } else if (idx < 263168) {               // params
            int p = idx - 262144;
            if (p < 128) {
                int c = ((p & 31) << 2) | (p >> 5);
                bqp[p] = bq[c] * QSC;            // 1/sqrt(dh) folded into q
            } else if (p < 384) {
                int r = p - 128; int rr = r & 127;
                int c = ((rr & 31) << 2) | (rr >> 5);
                bkvp[r] = (r < 128) ? bk[c] : bv[c];
            } else if (p < 640) {
                int o = p - 384;
                float bsum = 0.f;                // fold W1b @ bm into b1
                for (int j = 0; j < 128; j++)
                    bsum += W1[o * 384 + 256 + j] * bm[j];
                float s = g1[o] * rsqrtf(rv1[o] + 1e-5f);
                sc1[o] = s;
                sh1[o] = (b1[o] + bsum - rm1[o]) * s + be1[o];
            } else if (p < 896) {
                int o = p - 640;
                float s = g2[o] * rsqrtf(rv2[o] + 1e-5f);
                sc2[o] = s;
                sh2[o] = (b2[o] - rm2[o]) * s + be2[o];
            }
        }
    } else if (blockIdx.x == 1028) {             // ragged meta
        if (threadIdx.x == 0) {
            bool is64 = (sc_raw[1] == 0);        // counts in [256,512]
            int so = 0, dofs = 0;
            for (int i = 0; i < B_SEG; i++) {
                int s = is64 ? sc_raw[2 * i] : sc_raw[i];
                int d = is64 ? dc_raw[2 * i] : dc_raw[i];
                meta[i] = s; meta[64 + i] = d;
                meta[128 + i] = so; meta[192 + i] = dofs;
                so += s; dofs += d;
            }
        }
    } else {                                     // f32->bf16 convert (both acts)
        int i = (blockIdx.x - 1029) * 256 + threadIdx.x;
        int half = ntot * 64;
        const float4* s;
        u16* o;
        int j = i;
        if (i < half) { s = (const float4*)src_h; o = srcb; }
        else { s = (const float4*)dst_h; o = dstb; j = i - half; }
        float4 v = s[j];
        ushort4 u = {f2bf(v.x), f2bf(v.y), f2bf(v.z), f2bf(v.w)};
        ((ushort4*)o)[j] = u;
    }
}

// ============ generic 128x128 MFMA GEMM body, 2-phase double-buffered =======
// C[m][n] = sum_k Arow[m][k]*Bw[n][k]; A split at K1 -> A2. Al/Bl are
// [2][4096] u16 (two 8 KB buffers each). Per K-step: issue next-step
// global_load_lds into buf^1, compute current buf, ONE barrier (its implicit
// vmcnt(0) drain lands the prefetch AFTER the MFMA burst — T3 min-2-phase).
// Epilogue: v = acc*(flags&4?QSC:1)*scale[n] + shift[n]; relu(1); +resid;
// store f32(2) else bf16.
__device__ __forceinline__ void gemm_body(
    const u16* __restrict__ A, int lda,
    const u16* __restrict__ A2, int lda2, int K1,
    const u16* __restrict__ Bw, int K, int m0, int n0,
    const float* __restrict__ scale, const float* __restrict__ shift,
    const float* __restrict__ resid,
    void* __restrict__ Cout, int ldc, int flags,
    u16* Al, u16* Bl) {
    int tid = threadIdx.x;
    int w = tid >> 6, lane = tid & 63;
    int wm = w & 1, wn = w >> 1;
    int l15 = lane & 15, quad = lane >> 4;
    int srow = w * 32 + (lane >> 2);        // staging row (this call)
    int scol = (lane & 3) << 3;             // staging col (elems)
    f4v acc[4][4] = {};

    auto STAGE = [&](int buf, int k0) {
        const u16* Ag; int aL, acol;
        if (k0 < K1) { Ag = A; aL = lda; acol = k0; }
        else { Ag = A2; aL = lda2; acol = k0 - K1; }
        u16* al0 = Al + buf * 4096 + w * 1024;
        u16* bl0 = Bl + buf * 4096 + w * 1024;
        async_cp16(&Ag[(size_t)(m0 + srow) * aL + acol + scol], al0);
        async_cp16(&Ag[(size_t)(m0 + srow + 16) * aL + acol + scol], al0 + 512);
        async_cp16(&Bw[(size_t)(n0 + srow) * K + k0 + scol], bl0);
        async_cp16(&Bw[(size_t)(n0 + srow + 16) * K + k0 + scol], bl0 + 512);
    };

    STAGE(0, 0);
    __syncthreads();
    int cur = 0;
    for (int k0 = 0; k0 < K; k0 += 32) {
        if (k0 + 32 < K) STAGE(cur ^ 1, k0 + 32);
        const u16* Ab = Al + cur * 4096;
        const u16* Bb = Bl + cur * 4096;
        s8v af[4], bf[4];
#pragma unroll
        for (int i = 0; i < 4; i++)
            af[i] = *(const s8v*)(&Ab[(wm * 64 + i * 16 + l15) * 32 + quad * 8]);
#pragma unroll
        for (int j = 0; j < 4; j++)
            bf[j] = *(const s8v*)(&Bb[(wn * 64 + j * 16 + l15) * 32 + quad * 8]);
#pragma unroll
        for (int i = 0; i < 4; i++)
#pragma unroll
            for (int j = 0; j < 4; j++)
                acc[i][j] = __builtin_amdgcn_mfma_f32_16x16x32_bf16(
                    af[i], bf[j], acc[i][j], 0, 0, 0);
        __syncthreads();
        cur ^= 1;
    }
#pragma unroll
    for (int i = 0; i < 4; i++) {
#pragma unroll
        for (int j = 0; j < 4; j++) {
            int n = n0 + wn * 64 + j * 16 + l15;
            float sc = scale ? scale[n] : 1.f;
            float sh = shift ? shift[n] : 0.f;
#pragma unroll
            for (int r = 0; r < 4; r++) {
                int m = m0 + wm * 64 + i * 16 + quad * 4 + r;
                float v = acc[i][j][r];
                if (flags & 4) v *= QSC;
                v = v * sc + sh;
                if (flags & 1) v = fmaxf(v, 0.f);
                if (resid) v += resid[(size_t)m * 256 + n];
                if (flags & 2) ((float*)Cout)[(size_t)m * ldc + n] = v;
                else ((u16*)Cout)[(size_t)m * ldc + n] = f2bf(v);
            }
        }
    }
}

// fused q + k|v projections: y==0 -> q (with QSC fold), y==1,2 -> kv halves
__global__ __launch_bounds__(256) void k_qkv(
    const u16* __restrict__ dstb, const u16* __restrict__ srcb,
    const u16* __restrict__ pWq, const u16* __restrict__ pWkv,
    const float* __restrict__ bqp, const float* __restrict__ bkvp,
    u16* __restrict__ qb, u16* __restrict__ kvb) {
    __shared__ u16 Al[8192];    // 2 x 8 KB
    __shared__ u16 Bl[8192];
    int m0 = blockIdx.x * 128;
    if (blockIdx.y == 0)
        gemm_body(dstb, 256, dstb, 256, 256, pWq, 256, m0, 0,
                  nullptr, bqp, nullptr, qb, 128, 4, Al, Bl);
    else
        gemm_body(srcb, 256, srcb, 256, 256, pWkv, 256, m0, (blockIdx.y - 1) * 128,
                  nullptr, bkvp, nullptr, kvb, 256, 0, Al, Bl);
}

// ============ fused MLP: 32-row slab, x1 kept in LDS, 2-phase dbuf ==========
// Phase 1: x1 = relu(bn1([dstb|msgb] @ pW1f^T))  (M=32, N=256, K=384) -> LDS
// Phase 2: out = bn2(x1 @ pW2^T) + dst_h         (M=32, N=256, K=256), f32
// 4 waves; wave w owns cols w*64..w*64+63, all 32 rows. 52 KB LDS (dbuf) ->
// 3 blocks/CU. Phase-2's first W2 stage issued before the X1 epilogue so
// its latency hides under the epilogue VALU work.
// X1 XOR-swizzled: 16B slot s' = s ^ (row&7)  (conflict-free b128 reads).
__global__ __launch_bounds__(256, 4) void k_mlp(
    const u16* __restrict__ dstb, const u16* __restrict__ msgb,
    const u16* __restrict__ pW1f, const u16* __restrict__ pW2,
    const float* __restrict__ sc1, const float* __restrict__ sh1,
    const float* __restrict__ sc2, const float* __restrict__ sh2,
    const float* __restrict__ dst_h, float* __restrict__ out) {
    __shared__ u16 Al[2048];         // 2 x 2 KB A-stage
    __shared__ u16 Bl[16384];        // 2 x 16 KB B-stage
    __shared__ u16 X1[32 * 256];     // 16 KB x1 slab (swizzled)
    int m0 = blockIdx.x * 32;
    int tid = threadIdx.x;
    int w = tid >> 6, lane = tid & 63;
    int l15 = lane & 15, quad = lane >> 4;
    int srow = lane >> 2;                        // staging row within 16-row chunk
    int scol = (lane & 3) << 3;
    f4v acc[2][4];

    auto STAGE1 = [&](int buf, int k0) {
        const u16* Ag; int aL, acol;
        if (k0 < 256) { Ag = dstb; aL = 256; acol = k0; }
        else { Ag = msgb; aL = 128; acol = k0 - 256; }
#pragma unroll
        for (int q = 0; q < 4; q++)
            async_cp16(&pW1f[(size_t)(w * 64 + q * 16 + srow) * 384 + k0 + scol],
                       Bl + buf * 8192 + (w * 64 + q * 16) * 32);
        if (w < 2)
            async_cp16(&Ag[(size_t)(m0 + w * 16 + srow) * aL + acol + scol],
                       Al + buf * 1024 + w * 16 * 32);
    };
    auto STAGE2 = [&](int buf, int k0) {
#pragma unroll
        for (int q = 0; q < 4; q++)
            async_cp16(&pW2[(size_t)(w * 64 + q * 16 + srow) * 256 + k0 + scol],
                       Bl + buf * 8192 + (w * 64 + q * 16) * 32);
    };

    // ---- phase 1 ----
#pragma unroll
    for (int i = 0; i < 2; i++)
#pragma unroll
        for (int j = 0; j < 4; j++) acc[i][j] = (f4v){0.f, 0.f, 0.f, 0.f};

    STAGE1(0, 0);
    __syncthreads();
    int cur = 0;
    for (int k0 = 0; k0 < 384; k0 += 32) {
        if (k0 + 32 < 384) STAGE1(cur ^ 1, k0 + 32);
        const u16* Ab = Al + cur * 1024;
        const u16* Bb = Bl + cur * 8192;
        s8v af[2], bf[4];
#pragma unroll
        for (int i = 0; i < 2; i++)
            af[i] = *(const s8v*)(&Ab[(i * 16 + l15) * 32 + quad * 8]);
#pragma unroll
        for (int j = 0; j < 4; j++)
            bf[j] = *(const s8v*)(&Bb[(w * 64 + j * 16 + l15) * 32 + quad * 8]);
#pragma unroll
        for (int i = 0; i < 2; i++)
#pragma unroll
            for (int j = 0; j < 4; j++)
                acc[i][j] = __builtin_amdgcn_mfma_f32_16x16x32_bf16(
                    af[i], bf[j], acc[i][j], 0, 0, 0);
        __syncthreads();
        cur ^= 1;
    }

    // issue phase-2's first weight stage NOW (hides under epilogue VALU)
    STAGE2(0, 0);
    // epilogue 1 -> X1 (bf16, swizzled)
#pragma unroll
    for (int i = 0; i < 2; i++) {
#pragma unroll
        for (int j = 0; j < 4; j++) {
            int n = w * 64 + j * 16 + l15;
            float sc = sc1[n], sh = sh1[n];
#pragma unroll
            for (int r = 0; r < 4; r++) {
                int row = i * 16 + quad * 4 + r;
                float v = fmaxf(acc[i][j][r] * sc + sh, 0.f);
                X1[row * 256 + ((n >> 3) ^ (row & 7)) * 8 + (n & 7)] = f2bf(v);
            }
        }
    }
    __syncthreads();

    // ---- phase 2 ----
#pragma unroll
    for (int i = 0; i < 2; i++)
#pragma unroll
        for (int j = 0; j < 4; j++) acc[i][j] = (f4v){0.f, 0.f, 0.f, 0.f};

    cur = 0;
    for (int k0 = 0; k0 < 256; k0 += 32) {
        if (k0 + 32 < 256) STAGE2(cur ^ 1, k0 + 32);
        const u16* Bb = Bl + cur * 8192;
        s8v af[2], bf[4];
#pragma unroll
        for (int i = 0; i < 2; i++) {
            int row = i * 16 + l15;
            af[i] = *(const s8v*)(
                &X1[row * 256 + (((k0 >> 3) + quad) ^ (row & 7)) * 8]);
        }
#pragma unroll
        for (int j = 0; j < 4; j++)
            bf[j] = *(const s8v*)(&Bb[(w * 64 + j * 16 + l15) * 32 + quad * 8]);
#pragma unroll
        for (int i = 0; i < 2; i++)
#pragma unroll
            for (int j = 0; j < 4; j++)
                acc[i][j] = __builtin_amdgcn_mfma_f32_16x16x32_bf16(
                    af[i], bf[j], acc[i][j], 0, 0, 0);
        __syncthreads();
        cur ^= 1;
    }
    // epilogue 2 -> out (f32, + residual)
#pragma unroll
    for (int i = 0; i < 2; i++) {
#pragma unroll
        for (int j = 0; j < 4; j++) {
            int n = w * 64 + j * 16 + l15;
            float sc = sc2[n], sh = sh2[n];
#pragma unroll
            for (int r = 0; r < 4; r++) {
                int m = m0 + i * 16 + quad * 4 + r;
                float v = acc[i][j][r] * sc + sh + dst_h[(size_t)m * 256 + n];
                out[(size_t)m * 256 + n] = v;
            }
        }
    }
}

// ============ attention v8: K-from-global, V-only LDS, 1 strip/wave ========
// Block (b,h,z), z in {0,1,2,3}, 512 threads (8 waves). LDS = V^T [32][512]
// (slot^(row&7)) = 32768 B only -> 4 blocks/CU (128 KB), launch_bounds
// (512,8) -> 32 waves/CU ceiling. Wave (z,w) owns EXACTLY ONE 16-row strip
// s0=(z*8+w)*16 (bijective over rows 0..512) -> perfect ragged balance.
// K fragments read DIRECT from global (16B/lane, 16 rows x 64 B contiguous
// per wave = clean L2 coalescing) — v7 showed the swapped-QK^T A-frag needs
// no transpose, so K never needed LDS. Reads past segment end land inside
// d_out scratch (valid memory) and are masked by the ok-select before use.
// QK^T as mfma(K,Q) -> S^T; exp'd scores sit in the 16x16x16 B-frag layout;
// PV = mfma16(V^T-frag, P-frag), setprio(1) around the pure-MFMA cluster.
__global__ __launch_bounds__(512, 8) void k_attn(
    const u16* __restrict__ qb, const u16* __restrict__ kvb,
    const int* __restrict__ meta, u16* __restrict__ msgb) {
    extern __shared__ u16 sm[];
    u16* Vl = sm;                       // 32*512 elems = 32768 B
    int b = blockIdx.x, h = blockIdx.y, z = blockIdx.z;
    int ns = meta[b], nd = meta[64 + b];
    int soff = meta[128 + b], doff = meta[192 + b];
    int tid = threadIdx.x, w = tid >> 6, lane = tid & 63;
    int l15 = lane & 15, quad = lane >> 4;

    {   // stage V^T: one source row per thread, swizzled writes
        int m = tid;
        if (m < ns) {
            uint4 vv[4];
            const uint4* vs =
                (const uint4*)&kvb[(size_t)(soff + m) * 256 + 128 + h * 32];
#pragma unroll
            for (int s = 0; s < 4; s++) vv[s] = vs[s];
            const u16* pv = (const u16*)vv;
#pragma unroll
            for (int d = 0; d < 32; d++)
                Vl[d * 512 + ((m >> 3) ^ (d & 7)) * 8 + (m & 7)] = pv[d];
        } else {  // zero V tail (P=0 there; avoid 0*NaN)
#pragma unroll
            for (int d = 0; d < 32; d++)
                Vl[d * 512 + ((m >> 3) ^ (d & 7)) * 8 + (m & 7)] = 0;
        }
    }
    __syncthreads();

    int s0 = (z * 8 + w) * 16;          // this wave's single strip
    if (s0 >= nd) return;

    int nc32 = (ns + 31) >> 5;          // live 32-col chunks
    int vsw = l15 & 7;                  // V^T slot swizzle key (same for d,d+16)
    int half4 = (quad & 1) * 4;         // 8B half within 16B slot
    const u16* VlLo = Vl + l15 * 512;
    const u16* VlHi = Vl + (16 + l15) * 512;
    // K global base for this lane: row (soff + c*32 + l15), ch h*32+quad*8
    const u16* Kg = &kvb[(size_t)(soff + l15) * 256 + h * 32 + quad * 8];

    int qr = min(s0 + l15, nd - 1);
    s8v aq = *(const s8v*)&qb[(size_t)(doff + qr) * 128 + h * 32 + quad * 8];

    f4v oa0 = {0.f, 0.f, 0.f, 0.f};   // O^T rows d = quad*4+r
    f4v oa1 = {0.f, 0.f, 0.f, 0.f};   // O^T rows d = 16+quad*4+r
    float lsum = 0.f;
    for (int c = 0; c < nc32; c++) {
        // two K tiles (16 rows each) DIRECT from global, swapped operands
        s8v bk0 = *(const s8v*)&Kg[(size_t)(c * 32) * 256];
        s8v bk1 = *(const s8v*)&Kg[(size_t)(c * 32 + 16) * 256];
        f4v sa = __builtin_amdgcn_mfma_f32_16x16x32_bf16(
            bk0, aq, (f4v){0.f, 0.f, 0.f, 0.f}, 0, 0, 0);
        f4v sb = __builtin_amdgcn_mfma_f32_16x16x32_bf16(
            bk1, aq, (f4v){0.f, 0.f, 0.f, 0.f}, 0, 0, 0);
        int kb = c * 32 + quad * 4;       // this lane's k base (tile0)
        float e0[4], e1[4];
#pragma unroll
        for (int r = 0; r < 4; r++) {
            float va = (kb + r < ns) ? __expf(sa[r]) : 0.f;
            float vb = (kb + 16 + r < ns) ? __expf(sb[r]) : 0.f;
            e0[r] = va; e1[r] = vb;
            lsum += va + vb;
        }
        // P B-frags (k = quad*4+j within each 16-tile) — no exchange
        union { s4v v; u32 u[2]; } pb0, pb1;
        pb0.u[0] = (u32)f2bf(e0[0]) | ((u32)f2bf(e0[1]) << 16);
        pb0.u[1] = (u32)f2bf(e0[2]) | ((u32)f2bf(e0[3]) << 16);
        pb1.u[0] = (u32)f2bf(e1[0]) | ((u32)f2bf(e1[1]) << 16);
        pb1.u[1] = (u32)f2bf(e1[2]) | ((u32)f2bf(e1[3]) << 16);
        // V^T A-frags: k = c*32 + t*16 + quad*4 + j  (b64 reads)
        int slb = c * 4 + (quad >> 1);
        s4v v00 = *(const s4v*)&VlLo[(slb ^ vsw) * 8 + half4];
        s4v v01 = *(const s4v*)&VlLo[((slb + 2) ^ vsw) * 8 + half4];
        s4v v10 = *(const s4v*)&VlHi[(slb ^ vsw) * 8 + half4];
        s4v v11 = *(const s4v*)&VlHi[((slb + 2) ^ vsw) * 8 + half4];
        __builtin_amdgcn_s_setprio(1);
        oa0 = MFMA16(v00, pb0.v, oa0);
        oa0 = MFMA16(v01, pb1.v, oa0);
        oa1 = MFMA16(v10, pb0.v, oa1);
        oa1 = MFMA16(v11, pb1.v, oa1);
        __builtin_amdgcn_s_setprio(0);
    }
    // row-sum for q=l15: lane holds partial over its quad's k slots
    lsum += __shfl_xor(lsum, 16, 64);
    lsum += __shfl_xor(lsum, 32, 64);
    float inv = 1.f / lsum;           // already indexed by q=l15
    int row = s0 + l15;
    if (row < nd) {
        size_t base = (size_t)(doff + row) * 128 + h * 32;
        ushort4 o0 = {f2bf(oa0[0] * inv), f2bf(oa0[1] * inv),
                      f2bf(oa0[2] * inv), f2bf(oa0[3] * inv)};
        ushort4 o1 = {f2bf(oa1[0] * inv), f2bf(oa1[1] * inv),
                      f2bf(oa1[2] * inv), f2bf(oa1[3] * inv)};
        *(ushort4*)&msgb[base + quad * 4] = o0;
        *(ushort4*)&msgb[base + 16 + quad * 4] = o1;
    }
}

extern "C" void kernel_launch(void* const* d_in, const int* in_sizes, int n_in,
                              void* d_out, int out_size, void* d_ws, size_t ws_size,
                              hipStream_t stream) {
    const float* src_h = (const float*)d_in[0];
    const float* dst_h = (const float*)d_in[1];
    const int* snv = (const int*)d_in[2];
    const int* dnv = (const int*)d_in[3];
    const float* Wq = (const float*)d_in[4];  const float* bq = (const float*)d_in[5];
    const float* Wk = (const float*)d_in[6];  const float* bk = (const float*)d_in[7];
    const float* Wv = (const float*)d_in[8];  const float* bv = (const float*)d_in[9];
    const float* Wm = (const float*)d_in[10]; const float* bm = (const float*)d_in[11];
    const float* W1 = (const float*)d_in[12]; const float* b1 = (const float*)d_in[13];
    const float* g1 = (const float*)d_in[14]; const float* be1 = (const float*)d_in[15];
    const float* rm1 = (const float*)d_in[16]; const float* rv1 = (const float*)d_in[17];
    const float* W2 = (const float*)d_in[18]; const float* b2 = (const float*)d_in[19];
    const float* g2 = (const float*)d_in[20]; const float* be2 = (const float*)d_in[21];
    const float* rm2 = (const float*)d_in[22]; const float* rv2 = (const float*)d_in[23];

    int ntot = out_size / HDIM;  // 24576
    int mt = ntot / 128;         // 192

    // ws layout (~32.5 MB):
    char* ws = (char*)d_ws;
    int* meta = (int*)ws;
    float* bqp = (float*)(ws + 4096);           // 128
    float* bkvp = (float*)(ws + 4608);          // 256
    float* sc1 = (float*)(ws + 6144);           // 256
    float* sh1 = (float*)(ws + 7168);           // 256
    float* sc2 = (float*)(ws + 8192);           // 256
    float* sh2 = (float*)(ws + 9216);           // 256
    u16* pWq = (u16*)(ws + 16384);              // 32768 elems
    u16* pWkv = (u16*)(ws + 81920);             // 65536
    u16* pW1f = (u16*)(ws + 212992);            // 98304 (256x384)
    u16* pW2 = (u16*)(ws + 409600);             // 65536
    u16* srcb = (u16*)(ws + 1048576);           // ntot*256 bf16 (12.6 MB)
    u16* dstb = (u16*)(ws + 13631488);          // ntot*256 bf16 (12.6 MB)
    u16* msgb = (u16*)(ws + 26214400);          // ntot*128 bf16 (6.3 MB)

    // d_out doubles as q/kv scratch (consumed by k_attn before k_mlp writes):
    u16* qb = (u16*)d_out;                      // ntot*128
    u16* kvb = qb + (size_t)ntot * 128;         // ntot*256

    (void)hipFuncSetAttribute((const void*)k_attn,
                              hipFuncAttributeMaxDynamicSharedMemorySize, 32768);

    // 1) weights + meta + activation convert
    k_prep<<<dim3(1029 + ntot / 2), dim3(256), 0, stream>>>(
        Wq, bq, Wk, bk, Wv, bv, Wm, bm, W1, b1, g1, be1, rm1, rv1,
        W2, b2, g2, be2, rm2, rv2, snv, dnv, src_h, dst_h, meta,
        pWq, pWkv, pW1f, pW2, bqp, bkvp, sc1, sh1, sc2, sh2,
        srcb, dstb, ntot);
    // 2) q (QSC-folded) + k|v projections (2-phase dbuf)
    k_qkv<<<dim3(mt, 3), dim3(256), 0, stream>>>(
        dstb, srcb, pWq, pWkv, bqp, bkvp, qb, kvb);
    // 3) attention (8 waves, 32 KB LDS -> 4 blocks/CU, z=4, 1 strip/wave)
    k_attn<<<dim3(B_SEG, NHEADS, 4), dim3(512), 32768, stream>>>(
        qb, kvb, meta, msgb);
    // 4+5) fused MLP (2-phase dbuf): out = dst_h + bn2(relu(bn1([dstb|msgb]@W1'))@W2')
    k_mlp<<<dim3(ntot / 32), dim3(256), 0, stream>>>(
        dstb, msgb, pW1f, pW2, sc1, sh1, sc2, sh2, dst_h, (float*)d_out);
}

// Round 10
// 206.308 us; speedup vs baseline: 1.0254x; 1.0254x over previous
//
#include <hip/hip_runtime.h>
#include <hip/hip_bf16.h>
#include <math.h>

#define B_SEG 64
#define HDIM 256
#define HDIV 128
#define NHEADS 4
#define DH 32
#define QSC 0.17677669529663687f

typedef unsigned short u16;
typedef unsigned int u32;

typedef __attribute__((ext_vector_type(8))) short s8v;   // 8 x bf16
typedef __attribute__((ext_vector_type(4))) short s4v;   // 4 x bf16 (2 VGPR)
typedef __attribute__((ext_vector_type(4))) float f4v;   // mfma accum

// 16x16x16 bf16 MFMA: device pass picks the available builtin spelling;
// host pass gets an inert stub (R6 lesson: __has_builtin fails on host pass).
#if defined(__HIP_DEVICE_COMPILE__)
#if __has_builtin(__builtin_amdgcn_mfma_f32_16x16x16_bf16)
#define MFMA16(a, b, c) __builtin_amdgcn_mfma_f32_16x16x16_bf16(a, b, c, 0, 0, 0)
#elif __has_builtin(__builtin_amdgcn_mfma_f32_16x16x16bf16_1k)
#define MFMA16(a, b, c) __builtin_amdgcn_mfma_f32_16x16x16bf16_1k(a, b, c, 0, 0, 0)
#else
#error "no 16x16x16 bf16 mfma builtin on device"
#endif
#else
#define MFMA16(a, b, c) (c)
#endif

__device__ __forceinline__ u16 f2bf(float f) {
    u32 v;
    __builtin_memcpy(&v, &f, 4);
    u32 r = v + 0x7fffu + ((v >> 16) & 1u);
    return (u16)(r >> 16);
}

// async global->LDS, 16B per lane. LDS dest = wave-uniform base + lane*16.
__device__ __forceinline__ void async_cp16(const u16* g, u16* l) {
    __builtin_amdgcn_global_load_lds(
        (const __attribute__((address_space(1))) u32*)g,
        (__attribute__((address_space(3))) u32*)l, 16, 0, 0);
}

// T4 counted-vmcnt sync primitives (raw s_barrier, no full vmem drain).
__device__ __forceinline__ void wait_vm4() {
    asm volatile("s_waitcnt vmcnt(4)" ::: "memory");
}
__device__ __forceinline__ void wait_vm0() {
    asm volatile("s_waitcnt vmcnt(0)" ::: "memory");
}
__device__ __forceinline__ void wait_lgkm0() {
    asm volatile("s_waitcnt lgkmcnt(0)" ::: "memory");
}
__device__ __forceinline__ void bar() {
    __builtin_amdgcn_s_barrier();
}

// ============ prep: weights (bf16 + head-deinterleave + Wm-folding), meta,
// ============ activation f32->bf16 convert — one launch.
// head permute: dest channel c' = h*32+d <-> src c = d*4+h.
// pW1f = [W1[:,0:256] | W1[:,256:384] @ Wm'] (256 x 384); b1 absorbs W1b@bm.
__global__ __launch_bounds__(256) void k_prep(
    const float* __restrict__ Wq, const float* __restrict__ bq,
    const float* __restrict__ Wk, const float* __restrict__ bk,
    const float* __restrict__ Wv, const float* __restrict__ bv,
    const float* __restrict__ Wm, const float* __restrict__ bm,
    const float* __restrict__ W1, const float* __restrict__ b1,
    const float* __restrict__ g1, const float* __restrict__ be1,
    const float* __restrict__ rm1, const float* __restrict__ rv1,
    const float* __restrict__ W2, const float* __restrict__ b2,
    const float* __restrict__ g2, const float* __restrict__ be2,
    const float* __restrict__ rm2, const float* __restrict__ rv2,
    const int* __restrict__ sc_raw, const int* __restrict__ dc_raw,
    const float* __restrict__ src_h, const float* __restrict__ dst_h,
    int* __restrict__ meta,
    u16* __restrict__ pWq, u16* __restrict__ pWkv,
    u16* __restrict__ pW1f, u16* __restrict__ pW2,
    float* __restrict__ bqp, float* __restrict__ bkvp,
    float* __restrict__ sc1, float* __restrict__ sh1,
    float* __restrict__ sc2, float* __restrict__ sh2,
    u16* __restrict__ srcb, u16* __restrict__ dstb, int ntot) {
    if (blockIdx.x < 1028) {
        int idx = blockIdx.x * 256 + threadIdx.x;
        if (idx < 32768) {                       // Wq' rows permuted
            int cp = idx >> 8, k = idx & 255;
            int c = ((cp & 31) << 2) | (cp >> 5);
            pWq[idx] = f2bf(Wq[c * 256 + k]);
        } else if (idx < 98304) {                // Wkv': k rows 0..127, v 128..255
            int i = idx - 32768;
            int rp = i >> 8, k = i & 255;
            int r = rp & 127;
            int c = ((r & 31) << 2) | (r >> 5);
            float v = (rp < 128) ? Wk[c * 256 + k] : Wv[c * 256 + k];
            pWkv[i] = f2bf(v);
        } else if (idx < 163840) {               // W1 cols 0..255 plain
            int i = idx - 98304;
            int o = i >> 8, k = i & 255;
            pW1f[o * 384 + k] = f2bf(W1[o * 384 + k]);
        } else if (idx < 196608) {               // W1bm = W1b @ Wm' (cols 256..383)
            int i = idx - 163840;
            int o = i >> 7, cp = i & 127;
            int c = ((cp & 31) << 2) | (cp >> 5);
            float acc = 0.f;
            for (int j = 0; j < 128; j++)
                acc += W1[o * 384 + 256 + j] * Wm[j * 128 + c];
            pW1f[o * 384 + 256 + cp] = f2bf(acc);
        } else if (idx < 262144) {               // W2 plain
            int i = idx - 196608;
            pW2[i] = f2bf(W2[i]);
        } else if (idx < 263168) {               // params
            int p = idx - 262144;
            if (p < 128) {
                int c = ((p & 31) << 2) | (p >> 5);
                bqp[p] = bq[c] * QSC;            // 1/sqrt(dh) folded into q
            } else if (p < 384) {
                int r = p - 128; int rr = r & 127;
                int c = ((rr & 31) << 2) | (rr >> 5);
                bkvp[r] = (r < 128) ? bk[c] : bv[c];
            } else if (p < 640) {
                int o = p - 384;
                float bsum = 0.f;                // fold W1b @ bm into b1
                for (int j = 0; j < 128; j++)
                    bsum += W1[o * 384 + 256 + j] * bm[j];
                float s = g1[o] * rsqrtf(rv1[o] + 1e-5f);
                sc1[o] = s;
                sh1[o] = (b1[o] + bsum - rm1[o]) * s + be1[o];
            } else if (p < 896) {
                int o = p - 640;
                float s = g2[o] * rsqrtf(rv2[o] + 1e-5f);
                sc2[o] = s;
                sh2[o] = (b2[o] - rm2[o]) * s + be2[o];
            }
        }
    } else if (blockIdx.x == 1028) {             // ragged meta
        if (threadIdx.x == 0) {
            bool is64 = (sc_raw[1] == 0);        // counts in [256,512]
            int so = 0, dofs = 0;
            for (int i = 0; i < B_SEG; i++) {
                int s = is64 ? sc_raw[2 * i] : sc_raw[i];
                int d = is64 ? dc_raw[2 * i] : dc_raw[i];
                meta[i] = s; meta[64 + i] = d;
                meta[128 + i] = so; meta[192 + i] = dofs;
                so += s; dofs += d;
            }
        }
    } else {                                     // f32->bf16 convert (both acts)
        int i = (blockIdx.x - 1029) * 256 + threadIdx.x;
        int half = ntot * 64;
        const float4* s;
        u16* o;
        int j = i;
        if (i < half) { s = (const float4*)src_h; o = srcb; }
        else { s = (const float4*)dst_h; o = dstb; j = i - half; }
        float4 v = s[j];
        ushort4 u = {f2bf(v.x), f2bf(v.y), f2bf(v.z), f2bf(v.w)};
        ((ushort4*)o)[j] = u;
    }
}

// ============ generic 128x128 MFMA GEMM body, T4 counted-vmcnt pipeline ====
// C[m][n] = sum_k Arow[m][k]*Bw[n][k]; A split at K1 -> A2. Al/Bl are
// [2][4096] u16. Per K-step: issue next stage (4 loads) -> vmcnt(4) (waits
// only the OLDER buffer, one full iteration in flight) -> s_barrier ->
// ds_read+MFMA -> lgkmcnt(0) -> s_barrier. No vmcnt(0) drain in the loop
// (R8 lesson: __syncthreads' implicit drain defeated the double buffer).
__device__ __forceinline__ void gemm_body(
    const u16* __restrict__ A, int lda,
    const u16* __restrict__ A2, int lda2, int K1,
    const u16* __restrict__ Bw, int K, int m0, int n0,
    const float* __restrict__ scale, const float* __restrict__ shift,
    const float* __restrict__ resid,
    void* __restrict__ Cout, int ldc, int flags,
    u16* Al, u16* Bl) {
    int tid = threadIdx.x;
    int w = tid >> 6, lane = tid & 63;
    int wm = w & 1, wn = w >> 1;
    int l15 = lane & 15, quad = lane >> 4;
    int srow = w * 32 + (lane >> 2);        // staging row (this call)
    int scol = (lane & 3) << 3;             // staging col (elems)
    f4v acc[4][4] = {};

    auto STAGE = [&](int buf, int k0) {
        const u16* Ag; int aL, acol;
        if (k0 < K1) { Ag = A; aL = lda; acol = k0; }
        else { Ag = A2; aL = lda2; acol = k0 - K1; }
        u16* al0 = Al + buf * 4096 + w * 1024;
        u16* bl0 = Bl + buf * 4096 + w * 1024;
        async_cp16(&Ag[(size_t)(m0 + srow) * aL + acol + scol], al0);
        async_cp16(&Ag[(size_t)(m0 + srow + 16) * aL + acol + scol], al0 + 512);
        async_cp16(&Bw[(size_t)(n0 + srow) * K + k0 + scol], bl0);
        async_cp16(&Bw[(size_t)(n0 + srow + 16) * K + k0 + scol], bl0 + 512);
    };

    STAGE(0, 0);
    int cur = 0;
    for (int k0 = 0; k0 < K; k0 += 32) {
        if (k0 + 32 < K) { STAGE(cur ^ 1, k0 + 32); wait_vm4(); }
        else { wait_vm0(); }
        bar();                              // all waves' cur-buf loads landed
        const u16* Ab = Al + cur * 4096;
        const u16* Bb = Bl + cur * 4096;
        s8v af[4], bf[4];
#pragma unroll
        for (int i = 0; i < 4; i++)
            af[i] = *(const s8v*)(&Ab[(wm * 64 + i * 16 + l15) * 32 + quad * 8]);
#pragma unroll
        for (int j = 0; j < 4; j++)
            bf[j] = *(const s8v*)(&Bb[(wn * 64 + j * 16 + l15) * 32 + quad * 8]);
#pragma unroll
        for (int i = 0; i < 4; i++)
#pragma unroll
            for (int j = 0; j < 4; j++)
                acc[i][j] = __builtin_amdgcn_mfma_f32_16x16x32_bf16(
                    af[i], bf[j], acc[i][j], 0, 0, 0);
        wait_lgkm0();                       // reads retired before overwrite
        bar();
        cur ^= 1;
    }
#pragma unroll
    for (int i = 0; i < 4; i++) {
#pragma unroll
        for (int j = 0; j < 4; j++) {
            int n = n0 + wn * 64 + j * 16 + l15;
            float sc = scale ? scale[n] : 1.f;
            float sh = shift ? shift[n] : 0.f;
#pragma unroll
            for (int r = 0; r < 4; r++) {
                int m = m0 + wm * 64 + i * 16 + quad * 4 + r;
                float v = acc[i][j][r];
                if (flags & 4) v *= QSC;
                v = v * sc + sh;
                if (flags & 1) v = fmaxf(v, 0.f);
                if (resid) v += resid[(size_t)m * 256 + n];
                if (flags & 2) ((float*)Cout)[(size_t)m * ldc + n] = v;
                else ((u16*)Cout)[(size_t)m * ldc + n] = f2bf(v);
            }
        }
    }
}

// fused q + k|v projections: y==0 -> q (with QSC fold), y==1,2 -> kv halves
__global__ __launch_bounds__(256) void k_qkv(
    const u16* __restrict__ dstb, const u16* __restrict__ srcb,
    const u16* __restrict__ pWq, const u16* __restrict__ pWkv,
    const float* __restrict__ bqp, const float* __restrict__ bkvp,
    u16* __restrict__ qb, u16* __restrict__ kvb) {
    __shared__ u16 Al[8192];    // 2 x 8 KB
    __shared__ u16 Bl[8192];
    int m0 = blockIdx.x * 128;
    if (blockIdx.y == 0)
        gemm_body(dstb, 256, dstb, 256, 256, pWq, 256, m0, 0,
                  nullptr, bqp, nullptr, qb, 128, 4, Al, Bl);
    else
        gemm_body(srcb, 256, srcb, 256, 256, pWkv, 256, m0, (blockIdx.y - 1) * 128,
                  nullptr, bkvp, nullptr, kvb, 256, 0, Al, Bl);
}

// ============ fused MLP: 32-row slab, x1 in LDS, T4 counted-vmcnt pipeline ==
// Phase 1: x1 = relu(bn1([dstb|msgb] @ pW1f^T))  (M=32, N=256, K=384) -> LDS
// Phase 2: out = bn2(x1 @ pW2^T) + dst_h         (M=32, N=256, K=256), f32
// 4 waves; wave w owns cols w*64..w*64+63, all 32 rows. 52 KB LDS.
// X1 XOR-swizzled: 16B slot s' = s ^ (row&7)  (conflict-free b128 reads).
// vmcnt(4) is safe for the 5-load waves (w<2): over-waits one NEW load only.
__global__ __launch_bounds__(256, 4) void k_mlp(
    const u16* __restrict__ dstb, const u16* __restrict__ msgb,
    const u16* __restrict__ pW1f, const u16* __restrict__ pW2,
    const float* __restrict__ sc1, const float* __restrict__ sh1,
    const float* __restrict__ sc2, const float* __restrict__ sh2,
    const float* __restrict__ dst_h, float* __restrict__ out) {
    __shared__ u16 Al[2048];         // 2 x 2 KB A-stage
    __shared__ u16 Bl[16384];        // 2 x 16 KB B-stage
    __shared__ u16 X1[32 * 256];     // 16 KB x1 slab (swizzled)
    int m0 = blockIdx.x * 32;
    int tid = threadIdx.x;
    int w = tid >> 6, lane = tid & 63;
    int l15 = lane & 15, quad = lane >> 4;
    int srow = lane >> 2;                        // staging row within 16-row chunk
    int scol = (lane & 3) << 3;
    f4v acc[2][4];

    auto STAGE1 = [&](int buf, int k0) {
        const u16* Ag; int aL, acol;
        if (k0 < 256) { Ag = dstb; aL = 256; acol = k0; }
        else { Ag = msgb; aL = 128; acol = k0 - 256; }
#pragma unroll
        for (int q = 0; q < 4; q++)
            async_cp16(&pW1f[(size_t)(w * 64 + q * 16 + srow) * 384 + k0 + scol],
                       Bl + buf * 8192 + (w * 64 + q * 16) * 32);
        if (w < 2)
            async_cp16(&Ag[(size_t)(m0 + w * 16 + srow) * aL + acol + scol],
                       Al + buf * 1024 + w * 16 * 32);
    };
    auto STAGE2 = [&](int buf, int k0) {
#pragma unroll
        for (int q = 0; q < 4; q++)
            async_cp16(&pW2[(size_t)(w * 64 + q * 16 + srow) * 256 + k0 + scol],
                       Bl + buf * 8192 + (w * 64 + q * 16) * 32);
    };

    // ---- phase 1 ----
#pragma unroll
    for (int i = 0; i < 2; i++)
#pragma unroll
        for (int j = 0; j < 4; j++) acc[i][j] = (f4v){0.f, 0.f, 0.f, 0.f};

    STAGE1(0, 0);
    int cur = 0;
    for (int k0 = 0; k0 < 384; k0 += 32) {
        if (k0 + 32 < 384) { STAGE1(cur ^ 1, k0 + 32); wait_vm4(); }
        else { wait_vm0(); }
        bar();
        const u16* Ab = Al + cur * 1024;
        const u16* Bb = Bl + cur * 8192;
        s8v af[2], bf[4];
#pragma unroll
        for (int i = 0; i < 2; i++)
            af[i] = *(const s8v*)(&Ab[(i * 16 + l15) * 32 + quad * 8]);
#pragma unroll
        for (int j = 0; j < 4; j++)
            bf[j] = *(const s8v*)(&Bb[(w * 64 + j * 16 + l15) * 32 + quad * 8]);
#pragma unroll
        for (int i = 0; i < 2; i++)
#pragma unroll
            for (int j = 0; j < 4; j++)
                acc[i][j] = __builtin_amdgcn_mfma_f32_16x16x32_bf16(
                    af[i], bf[j], acc[i][j], 0, 0, 0);
        wait_lgkm0();
        bar();
        cur ^= 1;
    }

    // issue phase-2's first weight stage NOW (hides under epilogue VALU)
    STAGE2(0, 0);
    // epilogue 1 -> X1 (bf16, swizzled)
#pragma unroll
    for (int i = 0; i < 2; i++) {
#pragma unroll
        for (int j = 0; j < 4; j++) {
            int n = w * 64 + j * 16 + l15;
            float sc = sc1[n], sh = sh1[n];
#pragma unroll
            for (int r = 0; r < 4; r++) {
                int row = i * 16 + quad * 4 + r;
                float v = fmaxf(acc[i][j][r] * sc + sh, 0.f);
                X1[row * 256 + ((n >> 3) ^ (row & 7)) * 8 + (n & 7)] = f2bf(v);
            }
        }
    }
    __syncthreads();   // full drain: STAGE2(0) landed + X1 visible

    // ---- phase 2 ----
#pragma unroll
    for (int i = 0; i < 2; i++)
#pragma unroll
        for (int j = 0; j < 4; j++) acc[i][j] = (f4v){0.f, 0.f, 0.f, 0.f};

    cur = 0;
    for (int k0 = 0; k0 < 256; k0 += 32) {
        if (k0 + 32 < 256) { STAGE2(cur ^ 1, k0 + 32); wait_vm4(); }
        else { wait_vm0(); }
        bar();
        const u16* Bb = Bl + cur * 8192;
        s8v af[2], bf[4];
#pragma unroll
        for (int i = 0; i < 2; i++) {
            int row = i * 16 + l15;
            af[i] = *(const s8v*)(
                &X1[row * 256 + (((k0 >> 3) + quad) ^ (row & 7)) * 8]);
        }
#pragma unroll
        for (int j = 0; j < 4; j++)
            bf[j] = *(const s8v*)(&Bb[(w * 64 + j * 16 + l15) * 32 + quad * 8]);
#pragma unroll
        for (int i = 0; i < 2; i++)
#pragma unroll
            for (int j = 0; j < 4; j++)
                acc[i][j] = __builtin_amdgcn_mfma_f32_16x16x32_bf16(
                    af[i], bf[j], acc[i][j], 0, 0, 0);
        wait_lgkm0();
        bar();
        cur ^= 1;
    }
    // epilogue 2 -> out (f32, + residual)
#pragma unroll
    for (int i = 0; i < 2; i++) {
#pragma unroll
        for (int j = 0; j < 4; j++) {
            int n = w * 64 + j * 16 + l15;
            float sc = sc2[n], sh = sh2[n];
#pragma unroll
            for (int r = 0; r < 4; r++) {
                int m = m0 + i * 16 + quad * 4 + r;
                float v = acc[i][j][r] * sc + sh + dst_h[(size_t)m * 256 + n];
                out[(size_t)m * 256 + n] = v;
            }
        }
    }
}

// ============ attention v7 (reverted from v9's regression): swapped QK^T +
// 16x16x16 PV (O^T), zero shfl. Block (b,h,z), 512 threads (8 waves).
// LDS = K [512][32] (slot^((row>>1)&3)) + V^T [32][512] (slot^(row&7))
// = 65536 B -> 2 blocks/CU. z in {0,1}: wave w of block z owns strips
// (z*8+w), stride 256. QK^T as mfma(K,Q) -> S^T; exp'd scores sit in the
// 16x16x16 B-frag layout; PV = mfma16(V^T-frag, P-frag); inv per-lane.
__global__ __launch_bounds__(512, 4) void k_attn(
    const u16* __restrict__ qb, const u16* __restrict__ kvb,
    const int* __restrict__ meta, u16* __restrict__ msgb) {
    extern __shared__ u16 sm[];
    u16* Kl = sm;                       // 512*32 elems = 32768 B
    u16* Vl = sm + 16384;               // 32*512 elems = 32768 B
    int b = blockIdx.x, h = blockIdx.y, z = blockIdx.z;
    int ns = meta[b], nd = meta[64 + b];
    int soff = meta[128 + b], doff = meta[192 + b];
    int tid = threadIdx.x, w = tid >> 6, lane = tid & 63;
    int l15 = lane & 15, quad = lane >> 4;

    {   // stage K + V^T: one source row per thread, swizzled writes
        int m = tid;
        if (m < ns) {
            const uint4* ks = (const uint4*)&kvb[(size_t)(soff + m) * 256 + h * 32];
#pragma unroll
            for (int s = 0; s < 4; s++)
                *(uint4*)&Kl[m * 32 + (s ^ ((m >> 1) & 3)) * 8] = ks[s];
            uint4 vv[4];
            const uint4* vs =
                (const uint4*)&kvb[(size_t)(soff + m) * 256 + 128 + h * 32];
#pragma unroll
            for (int s = 0; s < 4; s++) vv[s] = vs[s];
            const u16* pv = (const u16*)vv;
#pragma unroll
            for (int d = 0; d < 32; d++)
                Vl[d * 512 + ((m >> 3) ^ (d & 7)) * 8 + (m & 7)] = pv[d];
        } else {  // zero V tail (P=0 there; avoid 0*NaN). K tail garbage is masked.
#pragma unroll
            for (int d = 0; d < 32; d++)
                Vl[d * 512 + ((m >> 3) ^ (d & 7)) * 8 + (m & 7)] = 0;
        }
    }
    __syncthreads();

    int nc32 = (ns + 31) >> 5;          // live 32-col chunks
    int ksw = (quad ^ ((l15 >> 1) & 3)) * 8;   // K read swizzle (row=..+l15)
    int vsw = l15 & 7;                  // V^T slot swizzle key (same for d,d+16)
    int half4 = (quad & 1) * 4;         // 8B half within 16B slot
    const u16* VlLo = Vl + l15 * 512;
    const u16* VlHi = Vl + (16 + l15) * 512;

    for (int s0 = (z * 8 + w) * 16; s0 < nd; s0 += 256) {  // 16 strips x 16 rows
        int qr = min(s0 + l15, nd - 1);
        s8v aq = *(const s8v*)&qb[(size_t)(doff + qr) * 128 + h * 32 + quad * 8];

        f4v oa0 = {0.f, 0.f, 0.f, 0.f};   // O^T rows d = quad*4+r
        f4v oa1 = {0.f, 0.f, 0.f, 0.f};   // O^T rows d = 16+quad*4+r
        float lsum = 0.f;
        for (int c = 0; c < nc32; c++) {
            // two K tiles (16 rows each), swapped operands -> S^T fragments
            int kr0 = c * 32 + l15;
            s8v bk0 = *(const s8v*)&Kl[kr0 * 32 + ksw];
            s8v bk1 = *(const s8v*)&Kl[(kr0 + 16) * 32 + ksw];
            f4v sa = __builtin_amdgcn_mfma_f32_16x16x32_bf16(
                bk0, aq, (f4v){0.f, 0.f, 0.f, 0.f}, 0, 0, 0);
            f4v sb = __builtin_amdgcn_mfma_f32_16x16x32_bf16(
                bk1, aq, (f4v){0.f, 0.f, 0.f, 0.f}, 0, 0, 0);
            int kb = c * 32 + quad * 4;       // this lane's k base (tile0)
            float e0[4], e1[4];
#pragma unroll
            for (int r = 0; r < 4; r++) {
                float va = (kb + r < ns) ? __expf(sa[r]) : 0.f;
                float vb = (kb + 16 + r < ns) ? __expf(sb[r]) : 0.f;
                e0[r] = va; e1[r] = vb;
                lsum += va + vb;
            }
            // P B-frags (k = quad*4+j within each 16-tile) — no exchange
            union { s4v v; u32 u[2]; } pb0, pb1;
            pb0.u[0] = (u32)f2bf(e0[0]) | ((u32)f2bf(e0[1]) << 16);
            pb0.u[1] = (u32)f2bf(e0[2]) | ((u32)f2bf(e0[3]) << 16);
            pb1.u[0] = (u32)f2bf(e1[0]) | ((u32)f2bf(e1[1]) << 16);
            pb1.u[1] = (u32)f2bf(e1[2]) | ((u32)f2bf(e1[3]) << 16);
            // V^T A-frags: k = c*32 + t*16 + quad*4 + j  (b64 reads)
            int slb = c * 4 + (quad >> 1);
            s4v v00 = *(const s4v*)&VlLo[(slb ^ vsw) * 8 + half4];
            s4v v01 = *(const s4v*)&VlLo[((slb + 2) ^ vsw) * 8 + half4];
            s4v v10 = *(const s4v*)&VlHi[(slb ^ vsw) * 8 + half4];
            s4v v11 = *(const s4v*)&VlHi[((slb + 2) ^ vsw) * 8 + half4];
            oa0 = MFMA16(v00, pb0.v, oa0);
            oa0 = MFMA16(v01, pb1.v, oa0);
            oa1 = MFMA16(v10, pb0.v, oa1);
            oa1 = MFMA16(v11, pb1.v, oa1);
        }
        // row-sum for q=l15: lane holds partial over its quad's k slots
        lsum += __shfl_xor(lsum, 16, 64);
        lsum += __shfl_xor(lsum, 32, 64);
        float inv = 1.f / lsum;           // already indexed by q=l15
        int row = s0 + l15;
        if (row < nd) {
            size_t base = (size_t)(doff + row) * 128 + h * 32;
            ushort4 o0 = {f2bf(oa0[0] * inv), f2bf(oa0[1] * inv),
                          f2bf(oa0[2] * inv), f2bf(oa0[3] * inv)};
            ushort4 o1 = {f2bf(oa1[0] * inv), f2bf(oa1[1] * inv),
                          f2bf(oa1[2] * inv), f2bf(oa1[3] * inv)};
            *(ushort4*)&msgb[base + quad * 4] = o0;
            *(ushort4*)&msgb[base + 16 + quad * 4] = o1;
        }
    }
}

extern "C" void kernel_launch(void* const* d_in, const int* in_sizes, int n_in,
                              void* d_out, int out_size, void* d_ws, size_t ws_size,
                              hipStream_t stream) {
    const float* src_h = (const float*)d_in[0];
    const float* dst_h = (const float*)d_in[1];
    const int* snv = (const int*)d_in[2];
    const int* dnv = (const int*)d_in[3];
    const float* Wq = (const float*)d_in[4];  const float* bq = (const float*)d_in[5];
    const float* Wk = (const float*)d_in[6];  const float* bk = (const float*)d_in[7];
    const float* Wv = (const float*)d_in[8];  const float* bv = (const float*)d_in[9];
    const float* Wm = (const float*)d_in[10]; const float* bm = (const float*)d_in[11];
    const float* W1 = (const float*)d_in[12]; const float* b1 = (const float*)d_in[13];
    const float* g1 = (const float*)d_in[14]; const float* be1 = (const float*)d_in[15];
    const float* rm1 = (const float*)d_in[16]; const float* rv1 = (const float*)d_in[17];
    const float* W2 = (const float*)d_in[18]; const float* b2 = (const float*)d_in[19];
    const float* g2 = (const float*)d_in[20]; const float* be2 = (const float*)d_in[21];
    const float* rm2 = (const float*)d_in[22]; const float* rv2 = (const float*)d_in[23];

    int ntot = out_size / HDIM;  // 24576
    int mt = ntot / 128;         // 192

    // ws layout (~32.5 MB):
    char* ws = (char*)d_ws;
    int* meta = (int*)ws;
    float* bqp = (float*)(ws + 4096);           // 128
    float* bkvp = (float*)(ws + 4608);          // 256
    float* sc1 = (float*)(ws + 6144);           // 256
    float* sh1 = (float*)(ws + 7168);           // 256
    float* sc2 = (float*)(ws + 8192);           // 256
    float* sh2 = (float*)(ws + 9216);           // 256
    u16* pWq = (u16*)(ws + 16384);              // 32768 elems
    u16* pWkv = (u16*)(ws + 81920);             // 65536
    u16* pW1f = (u16*)(ws + 212992);            // 98304 (256x384)
    u16* pW2 = (u16*)(ws + 409600);             // 65536
    u16* srcb = (u16*)(ws + 1048576);           // ntot*256 bf16 (12.6 MB)
    u16* dstb = (u16*)(ws + 13631488);          // ntot*256 bf16 (12.6 MB)
    u16* msgb = (u16*)(ws + 26214400);          // ntot*128 bf16 (6.3 MB)

    // d_out doubles as q/kv scratch (consumed by k_attn before k_mlp writes):
    u16* qb = (u16*)d_out;                      // ntot*128
    u16* kvb = qb + (size_t)ntot * 128;         // ntot*256

    (void)hipFuncSetAttribute((const void*)k_attn,
                              hipFuncAttributeMaxDynamicSharedMemorySize, 65536);

    // 1) weights + meta + activation convert
    k_prep<<<dim3(1029 + ntot / 2), dim3(256), 0, stream>>>(
        Wq, bq, Wk, bk, Wv, bv, Wm, bm, W1, b1, g1, be1, rm1, rv1,
        W2, b2, g2, be2, rm2, rv2, snv, dnv, src_h, dst_h, meta,
        pWq, pWkv, pW1f, pW2, bqp, bkvp, sc1, sh1, sc2, sh2,
        srcb, dstb, ntot);
    // 2) q (QSC-folded) + k|v projections (counted-vmcnt pipeline)
    k_qkv<<<dim3(mt, 3), dim3(256), 0, stream>>>(
        dstb, srcb, pWq, pWkv, bqp, bkvp, qb, kvb);
    // 3) attention v7 (8 waves, 64 KB LDS -> 2 blocks/CU, z=2)
    k_attn<<<dim3(B_SEG, NHEADS, 2), dim3(512), 65536, stream>>>(
        qb, kvb, meta, msgb);
    // 4+5) fused MLP (counted-vmcnt pipeline)
    k_mlp<<<dim3(ntot / 32), dim3(256), 0, stream>>>(
        dstb, msgb, pW1f, pW2, sc1, sh1, sc2, sh2, dst_h, (float*)d_out);
}

// Round 11
// 198.167 us; speedup vs baseline: 1.0675x; 1.0411x over previous
//
#include <hip/hip_runtime.h>
#include <hip/hip_bf16.h>
#include <math.h>

#define B_SEG 64
#define HDIM 256
#define HDIV 128
#define NHEADS 4
#define DH 32
#define QSC 0.17677669529663687f
// QSC * log2(e): q is consumed ONLY by exp(q.k), so folding log2e into the
// q-projection lets attn use a bare v_exp_f32 (exp2) with no per-element mul.
#define QSCL 0.2550760953483594f

typedef unsigned short u16;
typedef unsigned int u32;

typedef __attribute__((ext_vector_type(8))) short s8v;   // 8 x bf16
typedef __attribute__((ext_vector_type(4))) short s4v;   // 4 x bf16 (2 VGPR)
typedef __attribute__((ext_vector_type(4))) float f4v;   // mfma accum

// Device-pass builtin selection; host pass gets inert stubs (R6 lesson).
#if defined(__HIP_DEVICE_COMPILE__)
#if __has_builtin(__builtin_amdgcn_mfma_f32_16x16x16_bf16)
#define MFMA16(a, b, c) __builtin_amdgcn_mfma_f32_16x16x16_bf16(a, b, c, 0, 0, 0)
#elif __has_builtin(__builtin_amdgcn_mfma_f32_16x16x16bf16_1k)
#define MFMA16(a, b, c) __builtin_amdgcn_mfma_f32_16x16x16bf16_1k(a, b, c, 0, 0, 0)
#else
#error "no 16x16x16 bf16 mfma builtin on device"
#endif
#if __has_builtin(__builtin_amdgcn_exp2f)
#define EXP2(x) __builtin_amdgcn_exp2f(x)
#else
#define EXP2(x) exp2f(x)
#endif
#else
#define MFMA16(a, b, c) (c)
#define EXP2(x) exp2f(x)
#endif

__device__ __forceinline__ u16 f2bf(float f) {
    u32 v;
    __builtin_memcpy(&v, &f, 4);
    u32 r = v + 0x7fffu + ((v >> 16) & 1u);
    return (u16)(r >> 16);
}

// async global->LDS, 16B per lane. LDS dest = wave-uniform base + lane*16.
__device__ __forceinline__ void async_cp16(const u16* g, u16* l) {
    __builtin_amdgcn_global_load_lds(
        (const __attribute__((address_space(1))) u32*)g,
        (__attribute__((address_space(3))) u32*)l, 16, 0, 0);
}

// ============ prep: weights (bf16 + head-deinterleave + Wm-folding), meta,
// ============ activation f32->bf16 convert — one launch.
// head permute: dest channel c' = h*32+d <-> src c = d*4+h.
// pW1f = [W1[:,0:256] | W1[:,256:384] @ Wm'] (256 x 384); b1 absorbs W1b@bm.
__global__ __launch_bounds__(256) void k_prep(
    const float* __restrict__ Wq, const float* __restrict__ bq,
    const float* __restrict__ Wk, const float* __restrict__ bk,
    const float* __restrict__ Wv, const float* __restrict__ bv,
    const float* __restrict__ Wm, const float* __restrict__ bm,
    const float* __restrict__ W1, const float* __restrict__ b1,
    const float* __restrict__ g1, const float* __restrict__ be1,
    const float* __restrict__ rm1, const float* __restrict__ rv1,
    const float* __restrict__ W2, const float* __restrict__ b2,
    const float* __restrict__ g2, const float* __restrict__ be2,
    const float* __restrict__ rm2, const float* __restrict__ rv2,
    const int* __restrict__ sc_raw, const int* __restrict__ dc_raw,
    const float* __restrict__ src_h, const float* __restrict__ dst_h,
    int* __restrict__ meta,
    u16* __restrict__ pWq, u16* __restrict__ pWkv,
    u16* __restrict__ pW1f, u16* __restrict__ pW2,
    float* __restrict__ bqp, float* __restrict__ bkvp,
    float* __restrict__ sc1, float* __restrict__ sh1,
    float* __restrict__ sc2, float* __restrict__ sh2,
    u16* __restrict__ srcb, u16* __restrict__ dstb, int ntot) {
    if (blockIdx.x < 1028) {
        int idx = blockIdx.x * 256 + threadIdx.x;
        if (idx < 32768) {                       // Wq' rows permuted
            int cp = idx >> 8, k = idx & 255;
            int c = ((cp & 31) << 2) | (cp >> 5);
            pWq[idx] = f2bf(Wq[c * 256 + k]);
        } else if (idx < 98304) {                // Wkv': k rows 0..127, v 128..255
            int i = idx - 32768;
            int rp = i >> 8, k = i & 255;
            int r = rp & 127;
            int c = ((r & 31) << 2) | (r >> 5);
            float v = (rp < 128) ? Wk[c * 256 + k] : Wv[c * 256 + k];
            pWkv[i] = f2bf(v);
        } else if (idx < 163840) {               // W1 cols 0..255 plain
            int i = idx - 98304;
            int o = i >> 8, k = i & 255;
            pW1f[o * 384 + k] = f2bf(W1[o * 384 + k]);
        } else if (idx < 196608) {               // W1bm = W1b @ Wm' (cols 256..383)
            int i = idx - 163840;
            int o = i >> 7, cp = i & 127;
            int c = ((cp & 31) << 2) | (cp >> 5);
            float acc = 0.f;
            for (int j = 0; j < 128; j++)
                acc += W1[o * 384 + 256 + j] * Wm[j * 128 + c];
            pW1f[o * 384 + 256 + cp] = f2bf(acc);
        } else if (idx < 262144) {               // W2 plain
            int i = idx - 196608;
            pW2[i] = f2bf(W2[i]);
        } else if (idx < 263168) {               // params
            int p = idx - 262144;
            if (p < 128) {
                int c = ((p & 31) << 2) | (p >> 5);
                bqp[p] = bq[c] * QSCL;           // 1/sqrt(dh)*log2e folded into q
            } else if (p < 384) {
                int r = p - 128; int rr = r & 127;
                int c = ((rr & 31) << 2) | (rr >> 5);
                bkvp[r] = (r < 128) ? bk[c] : bv[c];
            } else if (p < 640) {
                int o = p - 384;
                float bsum = 0.f;                // fold W1b @ bm into b1
                for (int j = 0; j < 128; j++)
                    bsum += W1[o * 384 + 256 + j] * bm[j];
                float s = g1[o] * rsqrtf(rv1[o] + 1e-5f);
                sc1[o] = s;
                sh1[o] = (b1[o] + bsum - rm1[o]) * s + be1[o];
            } else if (p < 896) {
                int o = p - 640;
                float s = g2[o] * rsqrtf(rv2[o] + 1e-5f);
                sc2[o] = s;
                sh2[o] = (b2[o] - rm2[o]) * s + be2[o];
            }
        }
    } else if (blockIdx.x == 1028) {             // ragged meta
        if (threadIdx.x == 0) {
            bool is64 = (sc_raw[1] == 0);        // counts in [256,512]
            int so = 0, dofs = 0;
            for (int i = 0; i < B_SEG; i++) {
                int s = is64 ? sc_raw[2 * i] : sc_raw[i];
                int d = is64 ? dc_raw[2 * i] : dc_raw[i];
                meta[i] = s; meta[64 + i] = d;
                meta[128 + i] = so; meta[192 + i] = dofs;
                so += s; dofs += d;
            }
        }
    } else {                                     // f32->bf16 convert (both acts)
        int i = (blockIdx.x - 1029) * 256 + threadIdx.x;
        int half = ntot * 64;
        const float4* s;
        u16* o;
        int j = i;
        if (i < half) { s = (const float4*)src_h; o = srcb; }
        else { s = (const float4*)dst_h; o = dstb; j = i - half; }
        float4 v = s[j];
        ushort4 u = {f2bf(v.x), f2bf(v.y), f2bf(v.z), f2bf(v.w)};
        ((ushort4*)o)[j] = u;
    }
}

// ============ generic 128x128 MFMA GEMM body, 2-phase double-buffered =======
// (R8-verified structure: __syncthreads per step; counted-vmcnt variant was
// a measured regression, R10.) C[m][n] = sum_k Arow[m][k]*Bw[n][k]; A split
// at K1 -> A2. Al/Bl are [2][4096] u16. Epilogue: v = acc*(flags&4?QSCL:1)
// *scale[n] + shift[n]; relu(1); +resid[m*256+n]; store f32(2) else bf16.
__device__ __forceinline__ void gemm_body(
    const u16* __restrict__ A, int lda,
    const u16* __restrict__ A2, int lda2, int K1,
    const u16* __restrict__ Bw, int K, int m0, int n0,
    const float* __restrict__ scale, const float* __restrict__ shift,
    const float* __restrict__ resid,
    void* __restrict__ Cout, int ldc, int flags,
    u16* Al, u16* Bl) {
    int tid = threadIdx.x;
    int w = tid >> 6, lane = tid & 63;
    int wm = w & 1, wn = w >> 1;
    int l15 = lane & 15, quad = lane >> 4;
    int srow = w * 32 + (lane >> 2);        // staging row (this call)
    int scol = (lane & 3) << 3;             // staging col (elems)
    f4v acc[4][4] = {};

    auto STAGE = [&](int buf, int k0) {
        const u16* Ag; int aL, acol;
        if (k0 < K1) { Ag = A; aL = lda; acol = k0; }
        else { Ag = A2; aL = lda2; acol = k0 - K1; }
        u16* al0 = Al + buf * 4096 + w * 1024;
        u16* bl0 = Bl + buf * 4096 + w * 1024;
        async_cp16(&Ag[(size_t)(m0 + srow) * aL + acol + scol], al0);
        async_cp16(&Ag[(size_t)(m0 + srow + 16) * aL + acol + scol], al0 + 512);
        async_cp16(&Bw[(size_t)(n0 + srow) * K + k0 + scol], bl0);
        async_cp16(&Bw[(size_t)(n0 + srow + 16) * K + k0 + scol], bl0 + 512);
    };

    STAGE(0, 0);
    __syncthreads();
    int cur = 0;
    for (int k0 = 0; k0 < K; k0 += 32) {
        if (k0 + 32 < K) STAGE(cur ^ 1, k0 + 32);
        const u16* Ab = Al + cur * 4096;
        const u16* Bb = Bl + cur * 4096;
        s8v af[4], bf[4];
#pragma unroll
        for (int i = 0; i < 4; i++)
            af[i] = *(const s8v*)(&Ab[(wm * 64 + i * 16 + l15) * 32 + quad * 8]);
#pragma unroll
        for (int j = 0; j < 4; j++)
            bf[j] = *(const s8v*)(&Bb[(wn * 64 + j * 16 + l15) * 32 + quad * 8]);
#pragma unroll
        for (int i = 0; i < 4; i++)
#pragma unroll
            for (int j = 0; j < 4; j++)
                acc[i][j] = __builtin_amdgcn_mfma_f32_16x16x32_bf16(
                    af[i], bf[j], acc[i][j], 0, 0, 0);
        __syncthreads();
        cur ^= 1;
    }
#pragma unroll
    for (int i = 0; i < 4; i++) {
#pragma unroll
        for (int j = 0; j < 4; j++) {
            int n = n0 + wn * 64 + j * 16 + l15;
            float sc = scale ? scale[n] : 1.f;
            float sh = shift ? shift[n] : 0.f;
#pragma unroll
            for (int r = 0; r < 4; r++) {
                int m = m0 + wm * 64 + i * 16 + quad * 4 + r;
                float v = acc[i][j][r];
                if (flags & 4) v *= QSCL;
                v = v * sc + sh;
                if (flags & 1) v = fmaxf(v, 0.f);
                if (resid) v += resid[(size_t)m * 256 + n];
                if (flags & 2) ((float*)Cout)[(size_t)m * ldc + n] = v;
                else ((u16*)Cout)[(size_t)m * ldc + n] = f2bf(v);
            }
        }
    }
}

// fused q + k|v projections: y==0 -> q (with QSCL fold), y==1,2 -> kv halves
__global__ __launch_bounds__(256) void k_qkv(
    const u16* __restrict__ dstb, const u16* __restrict__ srcb,
    const u16* __restrict__ pWq, const u16* __restrict__ pWkv,
    const float* __restrict__ bqp, const float* __restrict__ bkvp,
    u16* __restrict__ qb, u16* __restrict__ kvb) {
    __shared__ u16 Al[8192];    // 2 x 8 KB
    __shared__ u16 Bl[8192];
    int m0 = blockIdx.x * 128;
    if (blockIdx.y == 0)
        gemm_body(dstb, 256, dstb, 256, 256, pWq, 256, m0, 0,
                  nullptr, bqp, nullptr, qb, 128, 4, Al, Bl);
    else
        gemm_body(srcb, 256, srcb, 256, 256, pWkv, 256, m0, (blockIdx.y - 1) * 128,
                  nullptr, bkvp, nullptr, kvb, 256, 0, Al, Bl);
}

// ============ fused MLP: 32-row slab, x1 kept in LDS, 2-phase dbuf ==========
// (R8-verified structure.) Phase 1: x1 = relu(bn1([dstb|msgb] @ pW1f^T))
// (M=32, N=256, K=384) -> LDS. Phase 2: out = bn2(x1 @ pW2^T) + dst_h, f32.
// 4 waves; wave w owns cols w*64..w*64+63, all 32 rows. 52 KB LDS.
// X1 XOR-swizzled: 16B slot s' = s ^ (row&7)  (conflict-free b128 reads).
__global__ __launch_bounds__(256, 4) void k_mlp(
    const u16* __restrict__ dstb, const u16* __restrict__ msgb,
    const u16* __restrict__ pW1f, const u16* __restrict__ pW2,
    const float* __restrict__ sc1, const float* __restrict__ sh1,
    const float* __restrict__ sc2, const float* __restrict__ sh2,
    const float* __restrict__ dst_h, float* __restrict__ out) {
    __shared__ u16 Al[2048];         // 2 x 2 KB A-stage
    __shared__ u16 Bl[16384];        // 2 x 16 KB B-stage
    __shared__ u16 X1[32 * 256];     // 16 KB x1 slab (swizzled)
    int m0 = blockIdx.x * 32;
    int tid = threadIdx.x;
    int w = tid >> 6, lane = tid & 63;
    int l15 = lane & 15, quad = lane >> 4;
    int srow = lane >> 2;                        // staging row within 16-row chunk
    int scol = (lane & 3) << 3;
    f4v acc[2][4];

    auto STAGE1 = [&](int buf, int k0) {
        const u16* Ag; int aL, acol;
        if (k0 < 256) { Ag = dstb; aL = 256; acol = k0; }
        else { Ag = msgb; aL = 128; acol = k0 - 256; }
#pragma unroll
        for (int q = 0; q < 4; q++)
            async_cp16(&pW1f[(size_t)(w * 64 + q * 16 + srow) * 384 + k0 + scol],
                       Bl + buf * 8192 + (w * 64 + q * 16) * 32);
        if (w < 2)
            async_cp16(&Ag[(size_t)(m0 + w * 16 + srow) * aL + acol + scol],
                       Al + buf * 1024 + w * 16 * 32);
    };
    auto STAGE2 = [&](int buf, int k0) {
#pragma unroll
        for (int q = 0; q < 4; q++)
            async_cp16(&pW2[(size_t)(w * 64 + q * 16 + srow) * 256 + k0 + scol],
                       Bl + buf * 8192 + (w * 64 + q * 16) * 32);
    };

    // ---- phase 1 ----
#pragma unroll
    for (int i = 0; i < 2; i++)
#pragma unroll
        for (int j = 0; j < 4; j++) acc[i][j] = (f4v){0.f, 0.f, 0.f, 0.f};

    STAGE1(0, 0);
    __syncthreads();
    int cur = 0;
    for (int k0 = 0; k0 < 384; k0 += 32) {
        if (k0 + 32 < 384) STAGE1(cur ^ 1, k0 + 32);
        const u16* Ab = Al + cur * 1024;
        const u16* Bb = Bl + cur * 8192;
        s8v af[2], bf[4];
#pragma unroll
        for (int i = 0; i < 2; i++)
            af[i] = *(const s8v*)(&Ab[(i * 16 + l15) * 32 + quad * 8]);
#pragma unroll
        for (int j = 0; j < 4; j++)
            bf[j] = *(const s8v*)(&Bb[(w * 64 + j * 16 + l15) * 32 + quad * 8]);
#pragma unroll
        for (int i = 0; i < 2; i++)
#pragma unroll
            for (int j = 0; j < 4; j++)
                acc[i][j] = __builtin_amdgcn_mfma_f32_16x16x32_bf16(
                    af[i], bf[j], acc[i][j], 0, 0, 0);
        __syncthreads();
        cur ^= 1;
    }

    // issue phase-2's first weight stage NOW (hides under epilogue VALU)
    STAGE2(0, 0);
    // epilogue 1 -> X1 (bf16, swizzled)
#pragma unroll
    for (int i = 0; i < 2; i++) {
#pragma unroll
        for (int j = 0; j < 4; j++) {
            int n = w * 64 + j * 16 + l15;
            float sc = sc1[n], sh = sh1[n];
#pragma unroll
            for (int r = 0; r < 4; r++) {
                int row = i * 16 + quad * 4 + r;
                float v = fmaxf(acc[i][j][r] * sc + sh, 0.f);
                X1[row * 256 + ((n >> 3) ^ (row & 7)) * 8 + (n & 7)] = f2bf(v);
            }
        }
    }
    __syncthreads();

    // ---- phase 2 ----
#pragma unroll
    for (int i = 0; i < 2; i++)
#pragma unroll
        for (int j = 0; j < 4; j++) acc[i][j] = (f4v){0.f, 0.f, 0.f, 0.f};

    cur = 0;
    for (int k0 = 0; k0 < 256; k0 += 32) {
        if (k0 + 32 < 256) STAGE2(cur ^ 1, k0 + 32);
        const u16* Bb = Bl + cur * 8192;
        s8v af[2], bf[4];
#pragma unroll
        for (int i = 0; i < 2; i++) {
            int row = i * 16 + l15;
            af[i] = *(const s8v*)(
                &X1[row * 256 + (((k0 >> 3) + quad) ^ (row & 7)) * 8]);
        }
#pragma unroll
        for (int j = 0; j < 4; j++)
            bf[j] = *(const s8v*)(&Bb[(w * 64 + j * 16 + l15) * 32 + quad * 8]);
#pragma unroll
        for (int i = 0; i < 2; i++)
#pragma unroll
            for (int j = 0; j < 4; j++)
                acc[i][j] = __builtin_amdgcn_mfma_f32_16x16x32_bf16(
                    af[i], bf[j], acc[i][j], 0, 0, 0);
        __syncthreads();
        cur ^= 1;
    }
    // epilogue 2 -> out (f32, + residual)
#pragma unroll
    for (int i = 0; i < 2; i++) {
#pragma unroll
        for (int j = 0; j < 4; j++) {
            int n = w * 64 + j * 16 + l15;
            float sc = sc2[n], sh = sh2[n];
#pragma unroll
            for (int r = 0; r < 4; r++) {
                int m = m0 + i * 16 + quad * 4 + r;
                float v = acc[i][j][r] * sc + sh + dst_h[(size_t)m * 256 + n];
                out[(size_t)m * 256 + n] = v;
            }
        }
    }
}

// ============ attention v7b: swapped QK^T + 16x16x16 PV (O^T), zero shfl ===
// Block (b,h,z), 512 threads (8 waves). LDS = K [512][32] (slot^((row>>1)&3))
// + V^T [32][512] (slot^(row&7)) = 65536 B -> 2 blocks/CU. z in {0,1}: wave w
// of block z owns strips (z*8+w), stride 256. QK^T as mfma(K,Q) -> S^T;
// log2e pre-folded into q so P = exp2(S) is a bare v_exp_f32; bound-check
// hoisted out of full chunks (only the ns&31 tail chunk masks). Exp'd scores
// sit in the 16x16x16 B-frag layout; PV = mfma16(V^T-frag, P-frag).
__global__ __launch_bounds__(512, 4) void k_attn(
    const u16* __restrict__ qb, const u16* __restrict__ kvb,
    const int* __restrict__ meta, u16* __restrict__ msgb) {
    extern __shared__ u16 sm[];
    u16* Kl = sm;                       // 512*32 elems = 32768 B
    u16* Vl = sm + 16384;               // 32*512 elems = 32768 B
    int b = blockIdx.x, h = blockIdx.y, z = blockIdx.z;
    int ns = meta[b], nd = meta[64 + b];
    int soff = meta[128 + b], doff = meta[192 + b];
    int tid = threadIdx.x, w = tid >> 6, lane = tid & 63;
    int l15 = lane & 15, quad = lane >> 4;

    {   // stage K + V^T: one source row per thread, swizzled writes
        int m = tid;
        if (m < ns) {
            const uint4* ks = (const uint4*)&kvb[(size_t)(soff + m) * 256 + h * 32];
#pragma unroll
            for (int s = 0; s < 4; s++)
                *(uint4*)&Kl[m * 32 + (s ^ ((m >> 1) & 3)) * 8] = ks[s];
            uint4 vv[4];
            const uint4* vs =
                (const uint4*)&kvb[(size_t)(soff + m) * 256 + 128 + h * 32];
#pragma unroll
            for (int s = 0; s < 4; s++) vv[s] = vs[s];
            const u16* pv = (const u16*)vv;
#pragma unroll
            for (int d = 0; d < 32; d++)
                Vl[d * 512 + ((m >> 3) ^ (d & 7)) * 8 + (m & 7)] = pv[d];
        } else {  // zero V tail (P=0 there; avoid 0*NaN). K tail garbage is masked.
#pragma unroll
            for (int d = 0; d < 32; d++)
                Vl[d * 512 + ((m >> 3) ^ (d & 7)) * 8 + (m & 7)] = 0;
        }
    }
    __syncthreads();

    int nfull = ns >> 5;                // chunks with all 32 k-cols valid
    int nc32 = (ns + 31) >> 5;          // total chunks
    int ksw = (quad ^ ((l15 >> 1) & 3)) * 8;   // K read swizzle (row=..+l15)
    int vsw = l15 & 7;                  // V^T slot swizzle key (same for d,d+16)
    int half4 = (quad & 1) * 4;         // 8B half within 16B slot
    const u16* VlLo = Vl + l15 * 512;
    const u16* VlHi = Vl + (16 + l15) * 512;

    for (int s0 = (z * 8 + w) * 16; s0 < nd; s0 += 256) {  // 16 strips x 16 rows
        int qr = min(s0 + l15, nd - 1);
        s8v aq = *(const s8v*)&qb[(size_t)(doff + qr) * 128 + h * 32 + quad * 8];

        f4v oa0 = {0.f, 0.f, 0.f, 0.f};   // O^T rows d = quad*4+r
        f4v oa1 = {0.f, 0.f, 0.f, 0.f};   // O^T rows d = 16+quad*4+r
        float lsum = 0.f;
        for (int c = 0; c < nc32; c++) {
            // two K tiles (16 rows each), swapped operands -> S^T fragments
            int kr0 = c * 32 + l15;
            s8v bk0 = *(const s8v*)&Kl[kr0 * 32 + ksw];
            s8v bk1 = *(const s8v*)&Kl[(kr0 + 16) * 32 + ksw];
            f4v sa = __builtin_amdgcn_mfma_f32_16x16x32_bf16(
                bk0, aq, (f4v){0.f, 0.f, 0.f, 0.f}, 0, 0, 0);
            f4v sb = __builtin_amdgcn_mfma_f32_16x16x32_bf16(
                bk1, aq, (f4v){0.f, 0.f, 0.f, 0.f}, 0, 0, 0);
            float e0[4], e1[4];
            if (c < nfull) {              // wave-uniform: no bound checks
#pragma unroll
                for (int r = 0; r < 4; r++) {
                    float va = EXP2(sa[r]);
                    float vb = EXP2(sb[r]);
                    e0[r] = va; e1[r] = vb;
                    lsum += va + vb;
                }
            } else {                      // tail chunk: mask k >= ns
                int kb = c * 32 + quad * 4;
#pragma unroll
                for (int r = 0; r < 4; r++) {
                    float va = (kb + r < ns) ? EXP2(sa[r]) : 0.f;
                    float vb = (kb + 16 + r < ns) ? EXP2(sb[r]) : 0.f;
                    e0[r] = va; e1[r] = vb;
                    lsum += va + vb;
                }
            }
            // P B-frags (k = quad*4+j within each 16-tile) — no exchange
            union { s4v v; u32 u[2]; } pb0, pb1;
            pb0.u[0] = (u32)f2bf(e0[0]) | ((u32)f2bf(e0[1]) << 16);
            pb0.u[1] = (u32)f2bf(e0[2]) | ((u32)f2bf(e0[3]) << 16);
            pb1.u[0] = (u32)f2bf(e1[0]) | ((u32)f2bf(e1[1]) << 16);
            pb1.u[1] = (u32)f2bf(e1[2]) | ((u32)f2bf(e1[3]) << 16);
            // V^T A-frags: k = c*32 + t*16 + quad*4 + j  (b64 reads)
            int slb = c * 4 + (quad >> 1);
            s4v v00 = *(const s4v*)&VlLo[(slb ^ vsw) * 8 + half4];
            s4v v01 = *(const s4v*)&VlLo[((slb + 2) ^ vsw) * 8 + half4];
            s4v v10 = *(const s4v*)&VlHi[(slb ^ vsw) * 8 + half4];
            s4v v11 = *(const s4v*)&VlHi[((slb + 2) ^ vsw) * 8 + half4];
            oa0 = MFMA16(v00, pb0.v, oa0);
            oa0 = MFMA16(v01, pb1.v, oa0);
            oa1 = MFMA16(v10, pb0.v, oa1);
            oa1 = MFMA16(v11, pb1.v, oa1);
        }
        // row-sum for q=l15: lane holds partial over its quad's k slots
        lsum += __shfl_xor(lsum, 16, 64);
        lsum += __shfl_xor(lsum, 32, 64);
        float inv = 1.f / lsum;           // already indexed by q=l15
        int row = s0 + l15;
        if (row < nd) {
            size_t base = (size_t)(doff + row) * 128 + h * 32;
            ushort4 o0 = {f2bf(oa0[0] * inv), f2bf(oa0[1] * inv),
                          f2bf(oa0[2] * inv), f2bf(oa0[3] * inv)};
            ushort4 o1 = {f2bf(oa1[0] * inv), f2bf(oa1[1] * inv),
                          f2bf(oa1[2] * inv), f2bf(oa1[3] * inv)};
            *(ushort4*)&msgb[base + quad * 4] = o0;
            *(ushort4*)&msgb[base + 16 + quad * 4] = o1;
        }
    }
}

extern "C" void kernel_launch(void* const* d_in, const int* in_sizes, int n_in,
                              void* d_out, int out_size, void* d_ws, size_t ws_size,
                              hipStream_t stream) {
    const float* src_h = (const float*)d_in[0];
    const float* dst_h = (const float*)d_in[1];
    const int* snv = (const int*)d_in[2];
    const int* dnv = (const int*)d_in[3];
    const float* Wq = (const float*)d_in[4];  const float* bq = (const float*)d_in[5];
    const float* Wk = (const float*)d_in[6];  const float* bk = (const float*)d_in[7];
    const float* Wv = (const float*)d_in[8];  const float* bv = (const float*)d_in[9];
    const float* Wm = (const float*)d_in[10]; const float* bm = (const float*)d_in[11];
    const float* W1 = (const float*)d_in[12]; const float* b1 = (const float*)d_in[13];
    const float* g1 = (const float*)d_in[14]; const float* be1 = (const float*)d_in[15];
    const float* rm1 = (const float*)d_in[16]; const float* rv1 = (const float*)d_in[17];
    const float* W2 = (const float*)d_in[18]; const float* b2 = (const float*)d_in[19];
    const float* g2 = (const float*)d_in[20]; const float* be2 = (const float*)d_in[21];
    const float* rm2 = (const float*)d_in[22]; const float* rv2 = (const float*)d_in[23];

    int ntot = out_size / HDIM;  // 24576
    int mt = ntot / 128;         // 192

    // ws layout (~32.5 MB):
    char* ws = (char*)d_ws;
    int* meta = (int*)ws;
    float* bqp = (float*)(ws + 4096);           // 128
    float* bkvp = (float*)(ws + 4608);          // 256
    float* sc1 = (float*)(ws + 6144);           // 256
    float* sh1 = (float*)(ws + 7168);           // 256
    float* sc2 = (float*)(ws + 8192);           // 256
    float* sh2 = (float*)(ws + 9216);           // 256
    u16* pWq = (u16*)(ws + 16384);              // 32768 elems
    u16* pWkv = (u16*)(ws + 81920);             // 65536
    u16* pW1f = (u16*)(ws + 212992);            // 98304 (256x384)
    u16* pW2 = (u16*)(ws + 409600);             // 65536
    u16* srcb = (u16*)(ws + 1048576);           // ntot*256 bf16 (12.6 MB)
    u16* dstb = (u16*)(ws + 13631488);          // ntot*256 bf16 (12.6 MB)
    u16* msgb = (u16*)(ws + 26214400);          // ntot*128 bf16 (6.3 MB)

    // d_out doubles as q/kv scratch (consumed by k_attn before k_mlp writes):
    u16* qb = (u16*)d_out;                      // ntot*128
    u16* kvb = qb + (size_t)ntot * 128;         // ntot*256

    (void)hipFuncSetAttribute((const void*)k_attn,
                              hipFuncAttributeMaxDynamicSharedMemorySize, 65536);

    // 1) weights + meta + activation convert
    k_prep<<<dim3(1029 + ntot / 2), dim3(256), 0, stream>>>(
        Wq, bq, Wk, bk, Wv, bv, Wm, bm, W1, b1, g1, be1, rm1, rv1,
        W2, b2, g2, be2, rm2, rv2, snv, dnv, src_h, dst_h, meta,
        pWq, pWkv, pW1f, pW2, bqp, bkvp, sc1, sh1, sc2, sh2,
        srcb, dstb, ntot);
    // 2) q (QSCL-folded) + k|v projections (2-phase dbuf)
    k_qkv<<<dim3(mt, 3), dim3(256), 0, stream>>>(
        dstb, srcb, pWq, pWkv, bqp, bkvp, qb, kvb);
    // 3) attention v7b (8 waves, 64 KB LDS -> 2 blocks/CU, z=2)
    k_attn<<<dim3(B_SEG, NHEADS, 2), dim3(512), 65536, stream>>>(
        qb, kvb, meta, msgb);
    // 4+5) fused MLP (2-phase dbuf)
    k_mlp<<<dim3(ntot / 32), dim3(256), 0, stream>>>(
        dstb, msgb, pW1f, pW2, sc1, sh1, sc2, sh2, dst_h, (float*)d_out);
}